// Round 4
// baseline (376.227 us; speedup 1.0000x reference)
//
#include <hip/hip_runtime.h>
#include <hip/hip_bf16.h>

typedef __attribute__((ext_vector_type(8)))  short short8;
typedef __attribute__((ext_vector_type(4)))  float f32x4;
typedef __attribute__((ext_vector_type(16))) float f32x16;

__device__ __forceinline__ unsigned short f2bf(float x) {
  __hip_bfloat16 h = __float2bfloat16(x);
  return (unsigned short)__builtin_bit_cast(short, h);
}
__device__ __forceinline__ unsigned packbf2(float lo, float hi2) {
  return (unsigned)f2bf(lo) | ((unsigned)f2bf(hi2) << 16);
}

// Repack W1 (43x256) and W2 (256x256) f32 row-major [k][h] into 32x32x16 bf16
// A-fragment order, and zero the output vector.
// Frag f = ks*8+mt: lane holds A[row = 32mt+(lane&31)][k = 16ks+8*(lane>>5)+i]
// = W[k][h]; stored at Wp[f*512 + lane*8 + i].  W1: 24 frags, W2: 128 frags.
__global__ void repack_zero(const float* __restrict__ W1, const float* __restrict__ W2,
                            short* __restrict__ Wp, float* __restrict__ out, int outn) {
  int id = blockIdx.x * 256 + threadIdx.x;
  if (blockIdx.x == 0 && threadIdx.x < outn) out[threadIdx.x] = 0.f;
  if (id >= 152 * 64) return;
  int fragidx = id >> 6, lane = id & 63;
  const float* W; int ks, mt, kmax;
  if (fragidx < 24) { W = W1; ks = fragidx >> 3; mt = fragidx & 7; kmax = 43; }
  else { int f2 = fragidx - 24; W = W2; ks = f2 >> 3; mt = f2 & 7; kmax = 256; }
  int h = 32 * mt + (lane & 31);
  int k0 = 16 * ks + 8 * (lane >> 5);
  short8 v;
  #pragma unroll
  for (int i = 0; i < 8; ++i) {
    int k = k0 + i;
    float x = (k < kmax) ? W[(long)k * 256 + h] : 0.f;
    v[i] = (short)f2bf(x);
  }
  *(short8*)(Wp + (long)fragidx * 512 + lane * 8) = v;
}

__device__ __forceinline__ short8 pack8(const float* v) {
  union { unsigned u[4]; short8 s; } c;
  #pragma unroll
  for (int j = 0; j < 4; ++j) c.u[j] = packbf2(v[2 * j], v[2 * j + 1]);
  return c.s;
}

__launch_bounds__(256, 2)
__global__ void srm2(const float* __restrict__ obs, const float* __restrict__ act,
                     const float* __restrict__ b1, const float* __restrict__ g1,
                     const float* __restrict__ be1,
                     const float* __restrict__ b2, const float* __restrict__ g2,
                     const float* __restrict__ be2,
                     const float* __restrict__ W3, const float* __restrict__ b3,
                     const short* __restrict__ Wp, float* __restrict__ out) {
  __shared__ float pb1[256], pg1[256], pe1[256];
  __shared__ float pb2[256], pg2[256], pe2[256], pw3[256];
  const int tid = threadIdx.x;
  pb1[tid] = b1[tid]; pg1[tid] = g1[tid]; pe1[tid] = be1[tid];
  pb2[tid] = b2[tid]; pg2[tid] = g2[tid]; pe2[tid] = be2[tid];
  pw3[tid] = W3[tid];
  const float b3v = b3[0];
  __syncthreads();

  const int wave = tid >> 6, lane = tid & 63;
  const int l31 = lane & 31, hi = lane >> 5;
  const int row0 = blockIdx.x * 128 + wave * 32;
  const int n = row0 + l31;          // this lane's sequence row
  const int bidx = row0 >> 11;       // 2048 rows per batch element

  // ---- X B-fragments: lane holds X[n][k], k = 16ks + 8hi + i (K padded to 48)
  const float* orow = obs + (long)n * 39;
  const float* arow = act + (long)n * 4;
  short8 bx0, bx1, bx2;
  {
    float v[8];
    #pragma unroll
    for (int i = 0; i < 8; ++i) v[i] = orow[8 * hi + i];
    bx0 = pack8(v);
    #pragma unroll
    for (int i = 0; i < 8; ++i) v[i] = orow[16 + 8 * hi + i];
    bx1 = pack8(v);
    #pragma unroll
    for (int i = 0; i < 8; ++i) {
      int k = 32 + 8 * hi + i;
      float t = 0.f;
      if (k < 39) t = orow[k]; else if (k < 43) t = arow[k - 39];
      v[i] = t;
    }
    bx2 = pack8(v);
  }

  const short8* W1v = (const short8*)Wp;                 // frags 0..23
  const short8* W2v = (const short8*)(Wp + 24L * 512);   // frags 0..127

  f32x16 acc[8];
  #pragma unroll
  for (int mt = 0; mt < 8; ++mt) acc[mt] = (f32x16)0.f;

  // ---------------- layer 1: D1[h][n] = W1^T tiles @ X^T ----------------
  #pragma unroll
  for (int ks = 0; ks < 3; ++ks) {
    const short8 bb = (ks == 0) ? bx0 : (ks == 1) ? bx1 : bx2;
    #pragma unroll
    for (int mt = 0; mt < 8; ++mt) {
      short8 a = W1v[(ks * 8 + mt) * 64 + lane];
      acc[mt] = __builtin_amdgcn_mfma_f32_32x32x16_bf16(a, bb, acc[mt], 0, 0, 0);
    }
  }

  // ---- LN1: bias + lane-local stats + one cross-half reduce ----
  // C layout: lane reg r=4qq+e holds D[h = 32mt+8qq+4hi+e][n]
  float mean1, rstd1;
  {
    float s = 0.f, q = 0.f;
    #pragma unroll
    for (int mt = 0; mt < 8; ++mt)
      #pragma unroll
      for (int qq = 0; qq < 4; ++qq) {
        const f32x4 b4 = *(const f32x4*)&pb1[32 * mt + 8 * qq + 4 * hi];
        #pragma unroll
        for (int e = 0; e < 4; ++e) {
          float t = acc[mt][4 * qq + e] + b4[e];
          acc[mt][4 * qq + e] = t;
          s += t; q += t * t;
        }
      }
    s += __shfl_xor(s, 32); q += __shfl_xor(q, 32);
    mean1 = s * (1.f / 256.f);
    rstd1 = rsqrtf(q * (1.f / 256.f) - mean1 * mean1 + 1e-5f);
  }

  // ---- LN1 apply + ReLU + pack to bf16 (register-resident H1) ----
  unsigned pk[8][4][2];
  #pragma unroll
  for (int mt = 0; mt < 8; ++mt)
    #pragma unroll
    for (int qq = 0; qq < 4; ++qq) {
      const int h0 = 32 * mt + 8 * qq + 4 * hi;
      const f32x4 g4 = *(const f32x4*)&pg1[h0];
      const f32x4 e4 = *(const f32x4*)&pe1[h0];
      float val[4];
      #pragma unroll
      for (int e = 0; e < 4; ++e) {
        float a = rstd1 * g4[e];
        float c = e4[e] - mean1 * a;
        val[e] = fmaxf(acc[mt][4 * qq + e] * a + c, 0.f);
      }
      pk[mt][qq][0] = packbf2(val[0], val[1]);
      pk[mt][qq][1] = packbf2(val[2], val[3]);
    }

  // ---------------- layer 2: D2[h][n] = W2^T tiles @ H1^T ----------------
  #pragma unroll
  for (int mt = 0; mt < 8; ++mt) acc[mt] = (f32x16)0.f;

  #pragma unroll
  for (int ks = 0; ks < 16; ++ks) {
    const int msrc = ks >> 1, q0 = 2 * (ks & 1), q1 = q0 + 1;
    // B-frag for this lane: k = 16ks + 8hi + i.  i<4 -> value held by the
    // hi=0 lane of the pair, i>=4 -> hi=1 lane; pack index q = 2(ks&1)+hi.
    unsigned c0 = hi ? pk[msrc][q0][0] : pk[msrc][q1][0];  // what partner needs
    unsigned c1 = hi ? pk[msrc][q0][1] : pk[msrc][q1][1];
    unsigned r0 = __shfl_xor(c0, 32), r1 = __shfl_xor(c1, 32);
    unsigned o0 = hi ? pk[msrc][q1][0] : pk[msrc][q0][0];  // own contribution
    unsigned o1 = hi ? pk[msrc][q1][1] : pk[msrc][q0][1];
    union { unsigned u[4]; short8 s; } bb;
    bb.u[0] = hi ? r0 : o0; bb.u[1] = hi ? r1 : o1;
    bb.u[2] = hi ? o0 : r0; bb.u[3] = hi ? o1 : r1;
    #pragma unroll
    for (int mt = 0; mt < 8; ++mt) {
      short8 a = W2v[(ks * 8 + mt) * 64 + lane];
      acc[mt] = __builtin_amdgcn_mfma_f32_32x32x16_bf16(a, bb.s, acc[mt], 0, 0, 0);
    }
  }

  // ---- LN2 stats ----
  float mean2, rstd2;
  {
    float s = 0.f, q = 0.f;
    #pragma unroll
    for (int mt = 0; mt < 8; ++mt)
      #pragma unroll
      for (int qq = 0; qq < 4; ++qq) {
        const f32x4 b4 = *(const f32x4*)&pb2[32 * mt + 8 * qq + 4 * hi];
        #pragma unroll
        for (int e = 0; e < 4; ++e) {
          float t = acc[mt][4 * qq + e] + b4[e];
          acc[mt][4 * qq + e] = t;
          s += t; q += t * t;
        }
      }
    s += __shfl_xor(s, 32); q += __shfl_xor(q, 32);
    mean2 = s * (1.f / 256.f);
    rstd2 = rsqrtf(q * (1.f / 256.f) - mean2 * mean2 + 1e-5f);
  }

  // ---- LN2 apply + ReLU + W3 dot + segment sum ----
  float p = 0.f;
  #pragma unroll
  for (int mt = 0; mt < 8; ++mt)
    #pragma unroll
    for (int qq = 0; qq < 4; ++qq) {
      const int h0 = 32 * mt + 8 * qq + 4 * hi;
      const f32x4 g4 = *(const f32x4*)&pg2[h0];
      const f32x4 e4 = *(const f32x4*)&pe2[h0];
      const f32x4 w4 = *(const f32x4*)&pw3[h0];
      #pragma unroll
      for (int e = 0; e < 4; ++e) {
        float a = rstd2 * g4[e];
        float c = e4[e] - mean2 * a;
        float val = fmaxf(acc[mt][4 * qq + e] * a + c, 0.f);
        p += val * w4[e];
      }
    }
  p += __shfl_xor(p, 32);     // complete each row's dot over all 256 h
  #pragma unroll
  for (int off = 1; off < 32; off <<= 1) p += __shfl_xor(p, off);  // sum 32 rows
  if (lane == 0) atomicAdd(&out[bidx], p + 32.f * b3v);
}

extern "C" void kernel_launch(void* const* d_in, const int* in_sizes, int n_in,
                              void* d_out, int out_size, void* d_ws, size_t ws_size,
                              hipStream_t stream) {
  const float* obs = (const float*)d_in[0];
  const float* act = (const float*)d_in[1];
  const float* W1  = (const float*)d_in[2];
  const float* b1  = (const float*)d_in[3];
  const float* g1  = (const float*)d_in[4];
  const float* be1 = (const float*)d_in[5];
  const float* W2  = (const float*)d_in[6];
  const float* b2  = (const float*)d_in[7];
  const float* g2  = (const float*)d_in[8];
  const float* be2 = (const float*)d_in[9];
  const float* W3  = (const float*)d_in[10];
  const float* b3  = (const float*)d_in[11];
  float* out = (float*)d_out;

  short* Wp = (short*)d_ws;   // 152 frags * 512 shorts = 152 KB

  repack_zero<<<38, 256, 0, stream>>>(W1, W2, Wp, out, out_size);

  const int n_rows = 256 * 2048;
  srm2<<<n_rows / 128, 256, 0, stream>>>(obs, act, b1, g1, be1,
                                         b2, g2, be2, W3, b3, Wp, out);
}

// Round 5
// 348.512 us; speedup vs baseline: 1.0795x; 1.0795x over previous
//
#include <hip/hip_runtime.h>
#include <hip/hip_bf16.h>

typedef __attribute__((ext_vector_type(8)))  short short8;
typedef __attribute__((ext_vector_type(4)))  float f32x4;
typedef __attribute__((ext_vector_type(16))) float f32x16;

__device__ __forceinline__ unsigned short f2bf(float x) {
  __hip_bfloat16 h = __float2bfloat16(x);
  return (unsigned short)__builtin_bit_cast(short, h);
}
__device__ __forceinline__ unsigned packbf2(float lo, float hi2) {
  return (unsigned)f2bf(lo) | ((unsigned)f2bf(hi2) << 16);
}
__device__ __forceinline__ short8 pack8(const float* v) {
  union { unsigned u[4]; short8 s; } c;
  #pragma unroll
  for (int j = 0; j < 4; ++j) c.u[j] = packbf2(v[2 * j], v[2 * j + 1]);
  return c.s;
}

// Pack W1 (43x256) and W2 (256x256) f32 row-major [k][h] into 32x32x16 bf16
// A-fragment order, and zero the output vector.
// Frag f = ks*8+mt: lane holds A[h = 32mt+(lane&31)][k = 16ks+8*(lane>>5)+i].
__global__ void repack_zero(const float* __restrict__ W1, const float* __restrict__ W2,
                            short* __restrict__ Wp, float* __restrict__ out, int outn) {
  int id = blockIdx.x * 256 + threadIdx.x;
  if (blockIdx.x == 0 && threadIdx.x < outn) out[threadIdx.x] = 0.f;
  if (id >= 152 * 64) return;
  int fragidx = id >> 6, lane = id & 63;
  const float* W; int ks, mt, kmax;
  if (fragidx < 24) { W = W1; ks = fragidx >> 3; mt = fragidx & 7; kmax = 43; }
  else { int f2 = fragidx - 24; W = W2; ks = f2 >> 3; mt = f2 & 7; kmax = 256; }
  int h = 32 * mt + (lane & 31);
  int k0 = 16 * ks + 8 * (lane >> 5);
  short8 v;
  #pragma unroll
  for (int i = 0; i < 8; ++i) {
    int k = k0 + i;
    float x = (k < kmax) ? W[(long)k * 256 + h] : 0.f;
    v[i] = (short)f2bf(x);
  }
  *(short8*)(Wp + (long)fragidx * 512 + lane * 8) = v;
}

#define TILES 8

__launch_bounds__(256, 2)
__global__ void srm3(const float* __restrict__ obs, const float* __restrict__ act,
                     const float* __restrict__ b1, const float* __restrict__ g1,
                     const float* __restrict__ be1,
                     const float* __restrict__ b2, const float* __restrict__ g2,
                     const float* __restrict__ be2,
                     const float* __restrict__ W3, const float* __restrict__ b3,
                     const short* __restrict__ Wp, float* __restrict__ out) {
  __shared__ float pb1[256], pg1[256], pe1[256];
  __shared__ float pb2[256], pg2[256], pe2[256], pw3[256];
  __shared__ float2 sq1[4][32], sq2[4][32];
  __shared__ short H1[32 * 256];   // 16 KB, XOR-swizzled rows

  const int tid = threadIdx.x;
  pb1[tid] = b1[tid]; pg1[tid] = g1[tid]; pe1[tid] = be1[tid];
  pb2[tid] = b2[tid]; pg2[tid] = g2[tid]; pe2[tid] = be2[tid];
  pw3[tid] = W3[tid];
  const float b3v = b3[0];

  const int wave = tid >> 6, lane = tid & 63;
  const int l31 = lane & 31, hi = lane >> 5;
  const int mt0 = 2 * wave;                 // this wave's h-tiles: mt0, mt0+1

  // ---- W fragments -> registers (held across the whole tile loop) ----
  const short8* W1v = (const short8*)Wp;
  const short8* W2v = (const short8*)(Wp + 24L * 512);
  short8 w1f[3][2], w2f[16][2];
  #pragma unroll
  for (int ks = 0; ks < 3; ++ks)
    #pragma unroll
    for (int j = 0; j < 2; ++j)
      w1f[ks][j] = W1v[(ks * 8 + mt0 + j) * 64 + lane];
  #pragma unroll
  for (int ks = 0; ks < 16; ++ks)
    #pragma unroll
    for (int j = 0; j < 2; ++j)
      w2f[ks][j] = W2v[(ks * 8 + mt0 + j) * 64 + lane];

  __syncthreads();

  const int blockRow0 = blockIdx.x * (TILES * 32);
  const int bidx = blockRow0 >> 11;
  const int swz = (l31 & 7) << 4;
  float ptot = 0.f;

  #pragma unroll 1
  for (int t = 0; t < TILES; ++t) {
    const long n = blockRow0 + t * 32 + l31;   // this lane's sequence row

    // ---- X B-fragments (k = 16ks + 8hi + i, K padded to 48) ----
    const float* orow = obs + n * 39;
    const float* arow = act + n * 4;
    short8 bx[3];
    {
      float v[8];
      #pragma unroll
      for (int i = 0; i < 8; ++i) v[i] = orow[8 * hi + i];
      bx[0] = pack8(v);
      #pragma unroll
      for (int i = 0; i < 8; ++i) v[i] = orow[16 + 8 * hi + i];
      bx[1] = pack8(v);
      #pragma unroll
      for (int i = 0; i < 8; ++i) {
        int k = 32 + 8 * hi + i;
        float tv = 0.f;
        if (k < 39) tv = orow[k]; else if (k < 43) tv = arow[k - 39];
        v[i] = tv;
      }
      bx[2] = pack8(v);
    }

    f32x16 acc[2];
    acc[0] = (f32x16)0.f; acc[1] = (f32x16)0.f;

    // ---- layer 1: D1[h][n], h in wave's 64-slice ----
    #pragma unroll
    for (int ks = 0; ks < 3; ++ks) {
      acc[0] = __builtin_amdgcn_mfma_f32_32x32x16_bf16(w1f[ks][0], bx[ks], acc[0], 0, 0, 0);
      acc[1] = __builtin_amdgcn_mfma_f32_32x32x16_bf16(w1f[ks][1], bx[ks], acc[1], 0, 0, 0);
    }

    // ---- LN1 partial stats (bias folded in) ----
    float s = 0.f, q = 0.f;
    #pragma unroll
    for (int j = 0; j < 2; ++j)
      #pragma unroll
      for (int qq = 0; qq < 4; ++qq) {
        const f32x4 b4 = *(const f32x4*)&pb1[32 * (mt0 + j) + 8 * qq + 4 * hi];
        #pragma unroll
        for (int e = 0; e < 4; ++e) {
          float tv = acc[j][4 * qq + e] + b4[e];
          acc[j][4 * qq + e] = tv;
          s += tv; q += tv * tv;
        }
      }
    s += __shfl_xor(s, 32); q += __shfl_xor(q, 32);
    if (lane < 32) sq1[wave][l31] = make_float2(s, q);
    __syncthreads();                                    // B1
    {
      float2 a0 = sq1[0][l31], a1 = sq1[1][l31], a2 = sq1[2][l31], a3 = sq1[3][l31];
      s = a0.x + a1.x + a2.x + a3.x;
      q = a0.y + a1.y + a2.y + a3.y;
    }
    float mean = s * (1.f / 256.f);
    float rstd = rsqrtf(q * (1.f / 256.f) - mean * mean + 1e-5f);

    // ---- LN1 apply + ReLU + pack -> H1 LDS (swizzled) ----
    #pragma unroll
    for (int j = 0; j < 2; ++j)
      #pragma unroll
      for (int qq = 0; qq < 4; ++qq) {
        const int h0 = 32 * (mt0 + j) + 8 * qq + 4 * hi;
        const f32x4 g4 = *(const f32x4*)&pg1[h0];
        const f32x4 e4 = *(const f32x4*)&pe1[h0];
        float val[4];
        #pragma unroll
        for (int e = 0; e < 4; ++e) {
          float a = rstd * g4[e];
          float c = e4[e] - mean * a;
          val[e] = fmaxf(acc[j][4 * qq + e] * a + c, 0.f);
        }
        unsigned lo = packbf2(val[0], val[1]);
        unsigned hiw = packbf2(val[2], val[3]);
        int byteoff = ((int)l31 * 512 + 2 * h0) ^ swz;
        *(uint2*)((char*)H1 + byteoff) = make_uint2(lo, hiw);
      }
    __syncthreads();                                    // B2 (H1 ready)

    // ---- layer 2: D2[h][n] over full K=256 ----
    acc[0] = (f32x16)0.f; acc[1] = (f32x16)0.f;
    #pragma unroll
    for (int ks = 0; ks < 16; ++ks) {
      int byteoff = ((int)l31 * 512 + 32 * ks + 16 * hi) ^ swz;
      short8 bb = *(const short8*)((const char*)H1 + byteoff);
      acc[0] = __builtin_amdgcn_mfma_f32_32x32x16_bf16(w2f[ks][0], bb, acc[0], 0, 0, 0);
      acc[1] = __builtin_amdgcn_mfma_f32_32x32x16_bf16(w2f[ks][1], bb, acc[1], 0, 0, 0);
    }

    // ---- LN2 partial stats ----
    s = 0.f; q = 0.f;
    #pragma unroll
    for (int j = 0; j < 2; ++j)
      #pragma unroll
      for (int qq = 0; qq < 4; ++qq) {
        const f32x4 b4 = *(const f32x4*)&pb2[32 * (mt0 + j) + 8 * qq + 4 * hi];
        #pragma unroll
        for (int e = 0; e < 4; ++e) {
          float tv = acc[j][4 * qq + e] + b4[e];
          acc[j][4 * qq + e] = tv;
          s += tv; q += tv * tv;
        }
      }
    s += __shfl_xor(s, 32); q += __shfl_xor(q, 32);
    if (lane < 32) sq2[wave][l31] = make_float2(s, q);
    __syncthreads();                                    // B3
    {
      float2 a0 = sq2[0][l31], a1 = sq2[1][l31], a2 = sq2[2][l31], a3 = sq2[3][l31];
      s = a0.x + a1.x + a2.x + a3.x;
      q = a0.y + a1.y + a2.y + a3.y;
    }
    float mean2 = s * (1.f / 256.f);
    float rstd2 = rsqrtf(q * (1.f / 256.f) - mean2 * mean2 + 1e-5f);

    // ---- LN2 apply + ReLU + W3 dot ----
    float p = 0.f;
    #pragma unroll
    for (int j = 0; j < 2; ++j)
      #pragma unroll
      for (int qq = 0; qq < 4; ++qq) {
        const int h0 = 32 * (mt0 + j) + 8 * qq + 4 * hi;
        const f32x4 g4 = *(const f32x4*)&pg2[h0];
        const f32x4 e4 = *(const f32x4*)&pe2[h0];
        const f32x4 w4 = *(const f32x4*)&pw3[h0];
        #pragma unroll
        for (int e = 0; e < 4; ++e) {
          float a = rstd2 * g4[e];
          float c = e4[e] - mean2 * a;
          float val = fmaxf(acc[j][4 * qq + e] * a + c, 0.f);
          p += val * w4[e];
        }
      }
    ptot += p;
  }

  // ---- block-level segment sum: one atomic per wave ----
  ptot += __shfl_xor(ptot, 32);
  #pragma unroll
  for (int off = 1; off < 32; off <<= 1) ptot += __shfl_xor(ptot, off);
  if (lane == 0) {
    float add = ptot + (wave == 0 ? (float)(TILES * 32) * b3v : 0.f);
    atomicAdd(&out[bidx], add);
  }
}

extern "C" void kernel_launch(void* const* d_in, const int* in_sizes, int n_in,
                              void* d_out, int out_size, void* d_ws, size_t ws_size,
                              hipStream_t stream) {
  const float* obs = (const float*)d_in[0];
  const float* act = (const float*)d_in[1];
  const float* W1  = (const float*)d_in[2];
  const float* b1  = (const float*)d_in[3];
  const float* g1  = (const float*)d_in[4];
  const float* be1 = (const float*)d_in[5];
  const float* W2  = (const float*)d_in[6];
  const float* b2  = (const float*)d_in[7];
  const float* g2  = (const float*)d_in[8];
  const float* be2 = (const float*)d_in[9];
  const float* W3  = (const float*)d_in[10];
  const float* b3  = (const float*)d_in[11];
  float* out = (float*)d_out;

  short* Wp = (short*)d_ws;   // 152 frags * 512 shorts = 152 KB

  repack_zero<<<38, 256, 0, stream>>>(W1, W2, Wp, out, out_size);

  const int n_rows = 256 * 2048;                 // 524288
  const int n_blocks = n_rows / (TILES * 32);    // 2048
  srm3<<<n_blocks, 256, 0, stream>>>(obs, act, b1, g1, be1,
                                     b2, g2, be2, W3, b3, Wp, out);
}